// Round 8
// baseline (406.870 us; speedup 1.0000x reference)
//
#include <hip/hip_runtime.h>
#include <math.h>

#define D 2048
#define E 64
#define TOK 64                 // tokens per block
#define THREADS 1024           // 16 waves = 16 K-chunks -> 4 waves/SIMD
#define NKC 16
#define KCH (D / NKC)          // 128 k-rows per wave
#define SK 8                   // k-rows per staged step
#define NSTEP (KCH / SK)       // 16

typedef float4 f4;

__device__ __forceinline__ float fget(const float4 v, int j) {
    return j == 0 ? v.x : j == 1 ? v.y : j == 2 ? v.z : v.w;
}

// 64 FMAs: outer product acc[8][8] += x8 (x) w8. All operands in VGPRs.
__device__ __forceinline__ void fmablock(float (&acc)[8][8],
                                         const float4 (&xw)[2],
                                         const float4 (&ww)[2]) {
#pragma unroll
    for (int t = 0; t < 8; ++t) {
        const float xt = fget(t < 4 ? xw[0] : xw[1], t & 3);
#pragma unroll
        for (int e = 0; e < 8; ++e) {
            const float we = fget(e < 4 ? ww[0] : ww[1], e & 3);
            acc[t][e] = fmaf(xt, we, acc[t][e]);
        }
    }
}

// Tree-tile IO on [64 tok][64 exp] fp32 (stride 64, b128-aligned; bank spread
// is 2x the b128 minimum-phase count -> ~free, epilogue-only anyway).
__device__ __forceinline__ void tile_store(float* b, const float (&acc)[8][8],
                                           int tg, int eg) {
#pragma unroll
    for (int t = 0; t < 8; ++t) {
        f4 v0 = {acc[t][0], acc[t][1], acc[t][2], acc[t][3]};
        f4 v1 = {acc[t][4], acc[t][5], acc[t][6], acc[t][7]};
        *(f4*)(b + (tg * 8 + t) * 64 + eg * 8) = v0;
        *(f4*)(b + (tg * 8 + t) * 64 + eg * 8 + 4) = v1;
    }
}

__device__ __forceinline__ void tile_addin(const float* b, float (&acc)[8][8],
                                           int tg, int eg) {
#pragma unroll
    for (int t = 0; t < 8; ++t) {
        f4 v0 = *(const f4*)(b + (tg * 8 + t) * 64 + eg * 8);
        f4 v1 = *(const f4*)(b + (tg * 8 + t) * 64 + eg * 8 + 4);
        acc[t][0] += v0.x; acc[t][1] += v0.y; acc[t][2] += v0.z; acc[t][3] += v0.w;
        acc[t][4] += v1.x; acc[t][5] += v1.y; acc[t][6] += v1.z; acc[t][7] += v1.w;
    }
}

// Round-7 post-mortem: structure was right (no spill, FETCH clean, absmax 0)
// but grid 256 x 4 waves = 1 wave/SIMD (Occupancy 10.6%) -> every LDS latency
// exposed; plus a 16-way bank conflict in the W-stage b128 write (5.85M cy).
// This round: 16 waves/block (4 waves/SIMD), same per-wave structure, and W
// staged as row-per-lane b32 (stride-1, conflict-free, same as the x scatter).
// LDS 128 KB -> physically 1 block/CU -> allocator targets 4 waves/EU ->
// 128-VGPR budget; live set ~112 fits (the r2/r3 spill trap can't trigger).
__global__ __launch_bounds__(THREADS)
void gating_kernel(const float* __restrict__ x,
                   const float* __restrict__ W,
                   const float* __restrict__ Bv,
                   float* __restrict__ out)
{
    __shared__ __align__(16) float smem[32768];    // 128 KB

    const int tid  = threadIdx.x;
    const int lane = tid & 63;
    const int w    = __builtin_amdgcn_readfirstlane(tid >> 6);  // K-chunk 0..15
    const int tg   = lane >> 3;          // token group (8 tokens)
    const int eg   = lane & 7;           // expert group (8 experts)
    const int tok0 = blockIdx.x * TOK;

    // per-wave private staging slices (2 KB tiles, double buffered, 8 KB/wave)
    float* base  = smem + w * 2048;
    float* xbuf0 = base;                 // xT [SK][64 tokens]
    float* xbuf1 = base + 512;
    float* wbuf0 = base + 1024;          // W  [SK][64 experts]
    float* wbuf1 = base + 1536;

    const float* xg = x + (size_t)(tok0 + lane) * D + w * KCH;  // lane=token (staging)
    const float* wg = W + (size_t)w * KCH * E;                  // [128][64]

    float acc[8][8];
#pragma unroll
    for (int t = 0; t < 8; ++t)
#pragma unroll
        for (int e = 0; e < 8; ++e) acc[t][e] = 0.f;

    float4 xs[2];              // this lane's token, 8 k-values
    float  ws[8];              // W rows j=0..7, this lane's expert column
    // ---- prologue: stage step 0 directly, issue step-1 loads, prime rows ----
    xs[0] = *(const f4*)(xg);
    xs[1] = *(const f4*)(xg + 4);
#pragma unroll
    for (int j = 0; j < 8; ++j) ws[j] = wg[j * E + lane];       // coalesced dword
#pragma unroll
    for (int j = 0; j < 8; ++j) xbuf0[j * 64 + lane] = fget(xs[j >> 2], j & 3);
#pragma unroll
    for (int j = 0; j < 8; ++j) wbuf0[j * 64 + lane] = ws[j];   // b32 stride-1
    xs[0] = *(const f4*)(xg + SK);
    xs[1] = *(const f4*)(xg + SK + 4);
#pragma unroll
    for (int j = 0; j < 8; ++j) ws[j] = wg[(SK + j) * E + lane];

    float4 xw[2][2], ww[2][2];
    xw[0][0] = *(const f4*)(xbuf0 + tg * 8);
    xw[0][1] = *(const f4*)(xbuf0 + tg * 8 + 4);
    ww[0][0] = *(const f4*)(wbuf0 + eg * 8);
    ww[0][1] = *(const f4*)(wbuf0 + eg * 8 + 4);
    xw[1][0] = *(const f4*)(xbuf0 + 64 + tg * 8);
    xw[1][1] = *(const f4*)(xbuf0 + 64 + tg * 8 + 4);
    ww[1][0] = *(const f4*)(wbuf0 + 64 + eg * 8);
    ww[1][1] = *(const f4*)(wbuf0 + 64 + eg * 8 + 4);

#pragma unroll 1
    for (int s = 0; s < NSTEP; ++s) {
        float* xc = (s & 1) ? xbuf1 : xbuf0;
        float* wc = (s & 1) ? wbuf1 : wbuf0;
        float* xn = (s & 1) ? xbuf0 : xbuf1;
        float* wn = (s & 1) ? wbuf0 : wbuf1;
        if (s < NSTEP - 1) {
            // write step s+1 tiles: globals issued a full step ago -> the
            // implied vmcnt wait is already satisfied. b32 stride-1 scatter,
            // conflict-free for BOTH x and W.
#pragma unroll
            for (int j = 0; j < 8; ++j) xn[j * 64 + lane] = fget(xs[j >> 2], j & 3);
#pragma unroll
            for (int j = 0; j < 8; ++j) wn[j * 64 + lane] = ws[j];
            // issue step s+2 globals
            const int s2 = (s + 2 < NSTEP) ? s + 2 : NSTEP - 1;
            xs[0] = *(const f4*)(xg + s2 * SK);
            xs[1] = *(const f4*)(xg + s2 * SK + 4);
#pragma unroll
            for (int j = 0; j < 8; ++j) ws[j] = wg[(s2 * SK + j) * E + lane];
        }
        const float* xnx = (s < NSTEP - 1) ? xn : xc;   // last step: dummy valid
        const float* wnx = (s < NSTEP - 1) ? wn : wc;
#pragma unroll
        for (int r = 0; r < SK; ++r) {
            const int p = r & 1;
            fmablock(acc, xw[p], ww[p]);               // 64 FMAs of cover
            // prefetch row r+2 (rows 6,7 cross into next step's tile, which
            // was written at the top of THIS step; same-wave DS is in-order)
            const float* xsrc = (r < SK - 2) ? (xc + (r + 2) * 64)
                                             : (xnx + (r - (SK - 2)) * 64);
            const float* wsrc = (r < SK - 2) ? (wc + (r + 2) * 64)
                                             : (wnx + (r - (SK - 2)) * 64);
            xw[p][0] = *(const f4*)(xsrc + tg * 8);
            xw[p][1] = *(const f4*)(xsrc + tg * 8 + 4);
            ww[p][0] = *(const f4*)(wsrc + eg * 8);
            ww[p][1] = *(const f4*)(wsrc + eg * 8 + 4);
        }
    }

    // ---- cross-wave K-reduction: 16 -> 8 -> 4 -> 2 -> 1 tile tree ----
    // tiles t at smem + t*4096 ([64][64]); staging slices dead after barrier.
    __syncthreads();
    if (w >= 8) tile_store(smem + (w - 8) * 4096, acc, tg, eg);
    __syncthreads();
    if (w < 8)  tile_addin(smem + w * 4096, acc, tg, eg);
    __syncthreads();
    if (w >= 4 && w < 8) tile_store(smem + (w - 4) * 4096, acc, tg, eg);
    __syncthreads();
    if (w < 4)  tile_addin(smem + w * 4096, acc, tg, eg);
    __syncthreads();
    if (w == 2 || w == 3) tile_store(smem + (w - 2) * 4096, acc, tg, eg);
    __syncthreads();
    if (w < 2)  tile_addin(smem + w * 4096, acc, tg, eg);
    __syncthreads();
    if (w == 1) tile_store(smem, acc, tg, eg);
    __syncthreads();

    float* logits = smem + 4096;          // [64][65], tile-1/2 region (dead)
    float* sw1 = smem + 8704; float* sw2 = smem + 8768;
    int*   si1 = (int*)(smem + 8832); int* si2 = (int*)(smem + 8896);

    if (w == 0) {
        tile_addin(smem, acc, tg, eg);    // full-K sums in acc
#pragma unroll
        for (int t = 0; t < 8; ++t)
#pragma unroll
            for (int e = 0; e < 8; ++e)
                logits[(tg * 8 + t) * 65 + eg * 8 + e] = acc[t][e];
    }
    __syncthreads();

    if (w == 0) {
        // lane = token: top-2 scan (+bias). Strict '>' matches top_k ties.
        float m1 = -3.4e38f, m2 = -3.4e38f;
        int i1 = 0, i2 = 0;
#pragma unroll
        for (int e = 0; e < E; ++e) {
            float v = logits[lane * 65 + e] + Bv[e];
            if (v > m1)      { m2 = m1; i2 = i1; m1 = v; i1 = e; }
            else if (v > m2) { m2 = v; i2 = e; }
        }
        float p = 1.0f / (1.0f + expf(m2 - m1));   // stable: m2 <= m1
        sw1[lane] = p; sw2[lane] = 1.0f - p;
        si1[lane] = i1; si2[lane] = i2;
    }
    __syncthreads();

    // ---- coalesced float4 store of the 64x64 tile (1024 float4) ----
    float4* o4 = (float4*)(out + (size_t)tok0 * E);
    {
        int idx = tid;                  // 0..1023
        int tl  = idx >> 4;             // token 0..63
        int e0  = (idx & 15) * 4;
        int a1 = si1[tl], a2 = si2[tl];
        float v1 = sw1[tl], v2 = sw2[tl];
        float4 v;
        v.x = (e0 + 0 == a1) ? v1 : (e0 + 0 == a2) ? v2 : 0.0f;
        v.y = (e0 + 1 == a1) ? v1 : (e0 + 1 == a2) ? v2 : 0.0f;
        v.z = (e0 + 2 == a1) ? v1 : (e0 + 2 == a2) ? v2 : 0.0f;
        v.w = (e0 + 3 == a1) ? v1 : (e0 + 3 == a2) ? v2 : 0.0f;
        o4[idx] = v;
    }
}

extern "C" void kernel_launch(void* const* d_in, const int* in_sizes, int n_in,
                              void* d_out, int out_size, void* d_ws, size_t ws_size,
                              hipStream_t stream) {
    const float* x = (const float*)d_in[0];
    const float* W = (const float*)d_in[1];
    const float* b = (const float*)d_in[2];
    float* out = (float*)d_out;

    const int tokens = in_sizes[0] / D;      // 16384
    const int blocks = tokens / TOK;         // 256

    gating_kernel<<<blocks, THREADS, 0, stream>>>(x, W, b, out);
}

// Round 9
// 223.994 us; speedup vs baseline: 1.8164x; 1.8164x over previous
//
#include <hip/hip_runtime.h>
#include <math.h>

#define D 2048
#define E 64
#define TOK 64                 // tokens per block (both kernels' tile)

typedef float4 f4;

__device__ __forceinline__ float fget(const float4 v, int j) {
    return j == 0 ? v.x : j == 1 ? v.y : j == 2 ? v.z : v.w;
}

// 64 FMAs: outer product acc[8][8] += x8 (x) w8. All operands in VGPRs.
// Per-lane 8 tok x 8 exp = 1 B/FMA of LDS read traffic (the minimum).
__device__ __forceinline__ void fmablock(float (&acc)[8][8],
                                         const float4 (&xw)[2],
                                         const float4 (&ww)[2]) {
#pragma unroll
    for (int t = 0; t < 8; ++t) {
        const float xt = fget(t < 4 ? xw[0] : xw[1], t & 3);
#pragma unroll
        for (int e = 0; e < 8; ++e) {
            const float we = fget(e < 4 ? ww[0] : ww[1], e & 3);
            acc[t][e] = fmaf(xt, we, acc[t][e]);
        }
    }
}

// Tree-tile IO on [64 tok][64 exp] fp32 (stride 64, b128-aligned; epilogue-only).
__device__ __forceinline__ void tile_store(float* b, const float (&acc)[8][8],
                                           int tg, int eg) {
#pragma unroll
    for (int t = 0; t < 8; ++t) {
        f4 v0 = {acc[t][0], acc[t][1], acc[t][2], acc[t][3]};
        f4 v1 = {acc[t][4], acc[t][5], acc[t][6], acc[t][7]};
        *(f4*)(b + (tg * 8 + t) * 64 + eg * 8) = v0;
        *(f4*)(b + (tg * 8 + t) * 64 + eg * 8 + 4) = v1;
    }
}

__device__ __forceinline__ void tile_addin(const float* b, float (&acc)[8][8],
                                           int tg, int eg) {
#pragma unroll
    for (int t = 0; t < 8; ++t) {
        f4 v0 = *(const f4*)(b + (tg * 8 + t) * 64 + eg * 8);
        f4 v1 = *(const f4*)(b + (tg * 8 + t) * 64 + eg * 8 + 4);
        acc[t][0] += v0.x; acc[t][1] += v0.y; acc[t][2] += v0.z; acc[t][3] += v0.w;
        acc[t][4] += v1.x; acc[t][5] += v1.y; acc[t][6] += v1.z; acc[t][7] += v1.w;
    }
}

// ---------------- kernel 1: K-quarter partial GEMM ----------------
// Round-8 post-mortem: 1024-thread blocks ALWAYS get a 64-VGPR allocation
// (4th data point) -> spill. Round 7 (256-thread block) got 140 VGPR, no
// spill; its only problem was grid=256 -> 1 wave/SIMD. Fix: split K across
// 4 blocks -> grid 1024 -> 3-4 blocks/CU (3 waves/SIMD at VGPR 140), keep
// the proven 4-wave block, r8's conflict-free b32 staging, and reduce the
// 4 quarter-partials in a tiny second kernel (r1-proven path).
#define NQ 4
#define KQ (D / NQ)            // 512 rows per block
#define KCH (KQ / 4)           // 128 rows per wave
#define SK 8                   // k-rows per staged step
#define NSTEP (KCH / SK)       // 16

__global__ __launch_bounds__(256)
void gating_mm(const float* __restrict__ x, const float* __restrict__ W,
               float* __restrict__ partial, int ntok)
{
    __shared__ __align__(16) float smem[8192];     // 32 KB

    const int tid  = threadIdx.x;
    const int lane = tid & 63;
    const int w    = __builtin_amdgcn_readfirstlane(tid >> 6);  // 0..3
    const int tg   = lane >> 3;          // token group (8 tokens)
    const int eg   = lane & 7;           // expert group (8 experts)
    const int q    = blockIdx.x & 3;     // K quarter
    const int tok0 = (blockIdx.x >> 2) * TOK;

    // per-wave private staging (2 KB slices, double buffered, 8 KB/wave)
    float* base  = smem + w * 2048;
    float* xbuf0 = base;                 // xT [SK][64 tokens]
    float* xbuf1 = base + 512;
    float* wbuf0 = base + 1024;          // W  [SK][64 experts]
    float* wbuf1 = base + 1536;

    const float* xg = x + (size_t)(tok0 + lane) * D + q * KQ + w * KCH;
    const float* wg = W + (size_t)(q * KQ + w * KCH) * E;

    float acc[8][8];
#pragma unroll
    for (int t = 0; t < 8; ++t)
#pragma unroll
        for (int e = 0; e < 8; ++e) acc[t][e] = 0.f;

    float4 xs[2];              // this lane's token, 8 k-values
    float  ws[8];              // W rows j=0..7, this lane's expert column
    // ---- prologue: stage step 0, issue step-1 loads, prime rows 0/1 ----
    xs[0] = *(const f4*)(xg);
    xs[1] = *(const f4*)(xg + 4);
#pragma unroll
    for (int j = 0; j < 8; ++j) ws[j] = wg[j * E + lane];       // coalesced dword
#pragma unroll
    for (int j = 0; j < 8; ++j) xbuf0[j * 64 + lane] = fget(xs[j >> 2], j & 3);
#pragma unroll
    for (int j = 0; j < 8; ++j) wbuf0[j * 64 + lane] = ws[j];   // b32 stride-1
    xs[0] = *(const f4*)(xg + SK);
    xs[1] = *(const f4*)(xg + SK + 4);
#pragma unroll
    for (int j = 0; j < 8; ++j) ws[j] = wg[(SK + j) * E + lane];

    float4 xw[2][2], ww[2][2];
    xw[0][0] = *(const f4*)(xbuf0 + tg * 8);
    xw[0][1] = *(const f4*)(xbuf0 + tg * 8 + 4);
    ww[0][0] = *(const f4*)(wbuf0 + eg * 8);
    ww[0][1] = *(const f4*)(wbuf0 + eg * 8 + 4);
    xw[1][0] = *(const f4*)(xbuf0 + 64 + tg * 8);
    xw[1][1] = *(const f4*)(xbuf0 + 64 + tg * 8 + 4);
    ww[1][0] = *(const f4*)(wbuf0 + 64 + eg * 8);
    ww[1][1] = *(const f4*)(wbuf0 + 64 + eg * 8 + 4);

#pragma unroll 1
    for (int s = 0; s < NSTEP; ++s) {
        float* xc = (s & 1) ? xbuf1 : xbuf0;
        float* wc = (s & 1) ? wbuf1 : wbuf0;
        float* xn = (s & 1) ? xbuf0 : xbuf1;
        float* wn = (s & 1) ? wbuf0 : wbuf1;
        if (s < NSTEP - 1) {
            // write step s+1 tiles: globals issued a full step ago -> the
            // implied vmcnt wait is already satisfied. b32 stride-1, no
            // bank conflicts for either x or W.
#pragma unroll
            for (int j = 0; j < 8; ++j) xn[j * 64 + lane] = fget(xs[j >> 2], j & 3);
#pragma unroll
            for (int j = 0; j < 8; ++j) wn[j * 64 + lane] = ws[j];
            // issue step s+2 globals
            const int s2 = (s + 2 < NSTEP) ? s + 2 : NSTEP - 1;
            xs[0] = *(const f4*)(xg + s2 * SK);
            xs[1] = *(const f4*)(xg + s2 * SK + 4);
#pragma unroll
            for (int j = 0; j < 8; ++j) ws[j] = wg[(s2 * SK + j) * E + lane];
        }
        const float* xnx = (s < NSTEP - 1) ? xn : xc;   // last step: dummy valid
        const float* wnx = (s < NSTEP - 1) ? wn : wc;
#pragma unroll
        for (int r = 0; r < SK; ++r) {
            const int p = r & 1;
            fmablock(acc, xw[p], ww[p]);               // 64 FMAs of cover
            // prefetch row r+2 (rows 6,7 cross into next step's tile, which
            // was written at the top of THIS step; same-wave DS is in-order)
            const float* xsrc = (r < SK - 2) ? (xc + (r + 2) * 64)
                                             : (xnx + (r - (SK - 2)) * 64);
            const float* wsrc = (r < SK - 2) ? (wc + (r + 2) * 64)
                                             : (wnx + (r - (SK - 2)) * 64);
            xw[p][0] = *(const f4*)(xsrc + tg * 8);
            xw[p][1] = *(const f4*)(xsrc + tg * 8 + 4);
            ww[p][0] = *(const f4*)(wsrc + eg * 8);
            ww[p][1] = *(const f4*)(wsrc + eg * 8 + 4);
        }
    }

    // ---- cross-wave K-reduction: 4 -> 2 -> 1 tile tree (32 KB reuse) ----
    __syncthreads();                     // staging slices dead
    if (w == 2) tile_store(smem, acc, tg, eg);
    if (w == 3) tile_store(smem + 4096, acc, tg, eg);
    __syncthreads();
    if (w == 0) tile_addin(smem, acc, tg, eg);
    if (w == 1) tile_addin(smem + 4096, acc, tg, eg);
    __syncthreads();
    if (w == 1) tile_store(smem, acc, tg, eg);
    __syncthreads();
    if (w == 0) {
        tile_addin(smem, acc, tg, eg);   // full quarter sum
        float* pq = partial + ((size_t)q * ntok + tok0) * E;
#pragma unroll
        for (int t = 0; t < 8; ++t) {
            f4 v0 = {acc[t][0], acc[t][1], acc[t][2], acc[t][3]};
            f4 v1 = {acc[t][4], acc[t][5], acc[t][6], acc[t][7]};
            *(f4*)(pq + (tg * 8 + t) * E + eg * 8) = v0;
            *(f4*)(pq + (tg * 8 + t) * E + eg * 8 + 4) = v1;
        }
    }
}

// ---------------- kernel 2: quarter-reduce + bias + top2 + scatter ----------------
__global__ __launch_bounds__(256)
void gating_topk(const float* __restrict__ partial, const float* __restrict__ Bv,
                 float* __restrict__ out, int ntok)
{
    __shared__ float logits[64][65];
    __shared__ float sw1[64], sw2[64];
    __shared__ int   si1[64], si2[64];

    const int tid  = threadIdx.x;
    const int tok0 = blockIdx.x * 64;
    const int tok  = tid >> 2;           // 0..63
    const int seg  = tid & 3;            // 16-float expert segment
    {
        float4 s[4];
        const float* p0 = partial + ((size_t)tok0 + tok) * E + seg * 16;
#pragma unroll
        for (int c = 0; c < 4; ++c) s[c] = *(const f4*)(p0 + 4 * c);
#pragma unroll
        for (int q = 1; q < 4; ++q) {
            const float* p = partial + ((size_t)q * ntok + tok0 + tok) * E + seg * 16;
#pragma unroll
            for (int c = 0; c < 4; ++c) {
                f4 v = *(const f4*)(p + 4 * c);
                s[c].x += v.x; s[c].y += v.y; s[c].z += v.z; s[c].w += v.w;
            }
        }
#pragma unroll
        for (int c = 0; c < 4; ++c) {
            f4 bv = *(const f4*)(Bv + seg * 16 + 4 * c);
            logits[tok][seg * 16 + 4*c + 0] = s[c].x + bv.x;
            logits[tok][seg * 16 + 4*c + 1] = s[c].y + bv.y;
            logits[tok][seg * 16 + 4*c + 2] = s[c].z + bv.z;
            logits[tok][seg * 16 + 4*c + 3] = s[c].w + bv.w;
        }
    }
    __syncthreads();

    if (tid < 64) {
        // lane = token: top-2 scan. Strict '>' matches top_k tie-breaking.
        float m1 = -3.4e38f, m2 = -3.4e38f;
        int i1 = 0, i2 = 0;
#pragma unroll
        for (int e = 0; e < E; ++e) {
            float v = logits[tid][e];
            if (v > m1)      { m2 = m1; i2 = i1; m1 = v; i1 = e; }
            else if (v > m2) { m2 = v; i2 = e; }
        }
        float p = 1.0f / (1.0f + expf(m2 - m1));   // stable: m2 <= m1
        sw1[tid] = p; sw2[tid] = 1.0f - p;
        si1[tid] = i1; si2[tid] = i2;
    }
    __syncthreads();

    float4* o4 = (float4*)(out + (size_t)tok0 * E);
#pragma unroll
    for (int p5 = 0; p5 < 4; ++p5) {
        int idx = tid + p5 * 256;        // 0..1023 float4s of the 64x64 tile
        int tl  = idx >> 4;
        int e0  = (idx & 15) * 4;
        int a1 = si1[tl], a2 = si2[tl];
        float v1 = sw1[tl], v2 = sw2[tl];
        float4 v;
        v.x = (e0 + 0 == a1) ? v1 : (e0 + 0 == a2) ? v2 : 0.0f;
        v.y = (e0 + 1 == a1) ? v1 : (e0 + 1 == a2) ? v2 : 0.0f;
        v.z = (e0 + 2 == a1) ? v1 : (e0 + 2 == a2) ? v2 : 0.0f;
        v.w = (e0 + 3 == a1) ? v1 : (e0 + 3 == a2) ? v2 : 0.0f;
        o4[idx] = v;
    }
}

// ---------------- fallback: round-7 verified single-kernel path ----------------
#define FKCH 512
#define FSK 16
#define FNSTEP (FKCH / FSK)    // 32

__device__ __forceinline__ void fb_tile_store(float* b, const float (&acc)[8][8],
                                              int tg, int eg) {
#pragma unroll
    for (int t = 0; t < 8; ++t) {
        f4 v0 = {acc[t][0], acc[t][1], acc[t][2], acc[t][3]};
        f4 v1 = {acc[t][4], acc[t][5], acc[t][6], acc[t][7]};
        *(f4*)(b + (tg * 8 + t) * 65 + eg * 8) = v0;
        *(f4*)(b + (tg * 8 + t) * 65 + eg * 8 + 4) = v1;
    }
}

__device__ __forceinline__ void fb_tile_addin(const float* b, float (&acc)[8][8],
                                              int tg, int eg) {
#pragma unroll
    for (int t = 0; t < 8; ++t) {
        f4 v0 = *(const f4*)(b + (tg * 8 + t) * 65 + eg * 8);
        f4 v1 = *(const f4*)(b + (tg * 8 + t) * 65 + eg * 8 + 4);
        acc[t][0] += v0.x; acc[t][1] += v0.y; acc[t][2] += v0.z; acc[t][3] += v0.w;
        acc[t][4] += v1.x; acc[t][5] += v1.y; acc[t][6] += v1.z; acc[t][7] += v1.w;
    }
}

__global__ __launch_bounds__(256)
void gating_fb(const float* __restrict__ x, const float* __restrict__ W,
               const float* __restrict__ Bv, float* __restrict__ out)
{
    __shared__ __align__(16) float smem[16384];

    const int tid  = threadIdx.x;
    const int lane = tid & 63;
    const int w    = __builtin_amdgcn_readfirstlane(tid >> 6);
    const int tg   = lane >> 3;
    const int eg   = lane & 7;
    const int tok0 = blockIdx.x * TOK;

    float* base  = smem + w * 4096;
    float* xbuf0 = base;
    float* xbuf1 = base + 1024;
    float* wbuf0 = base + 2048;
    float* wbuf1 = base + 3072;

    const float* xg = x + (size_t)(tok0 + lane) * D + w * FKCH;
    const float* wg = W + (size_t)w * FKCH * E;

    float acc[8][8];
#pragma unroll
    for (int t = 0; t < 8; ++t)
#pragma unroll
        for (int e = 0; e < 8; ++e) acc[t][e] = 0.f;

    float4 xs[4];
    float  ws[16];
#pragma unroll
    for (int c = 0; c < 4; ++c) xs[c] = *(const f4*)(xg + c * 4);
#pragma unroll
    for (int j = 0; j < 16; ++j) ws[j] = wg[j * E + lane];
#pragma unroll
    for (int j = 0; j < 16; ++j) xbuf0[j * 64 + lane] = fget(xs[j >> 2], j & 3);
#pragma unroll
    for (int j = 0; j < 16; ++j) wbuf0[j * 64 + lane] = ws[j];
#pragma unroll
    for (int c = 0; c < 4; ++c) xs[c] = *(const f4*)(xg + FSK + c * 4);
#pragma unroll
    for (int j = 0; j < 16; ++j) ws[j] = wg[(FSK + j) * E + lane];

    float4 xw[2][2], ww[2][2];
    xw[0][0] = *(const f4*)(xbuf0 + tg * 8);
    xw[0][1] = *(const f4*)(xbuf0 + tg * 8 + 4);
    ww[0][0] = *(const f4*)(wbuf0 + eg * 8);
    ww[0][1] = *(const f4*)(wbuf0 + eg * 8 + 4);
    xw[1][0] = *(const f4*)(xbuf0 + 64 + tg * 8);
    xw[1][1] = *(const f4*)(xbuf0 + 64 + tg * 8 + 4);
    ww[1][0] = *(const f4*)(wbuf0 + 64 + eg * 8);
    ww[1][1] = *(const f4*)(wbuf0 + 64 + eg * 8 + 4);

#pragma unroll 1
    for (int s = 0; s < FNSTEP; ++s) {
        float* xc = (s & 1) ? xbuf1 : xbuf0;
        float* wc = (s & 1) ? wbuf1 : wbuf0;
        float* xn = (s & 1) ? xbuf0 : xbuf1;
        float* wn = (s & 1) ? wbuf0 : wbuf1;
        if (s < FNSTEP - 1) {
#pragma unroll
            for (int j = 0; j < 16; ++j) xn[j * 64 + lane] = fget(xs[j >> 2], j & 3);
#pragma unroll
            for (int j = 0; j < 16; ++j) wn[j * 64 + lane] = ws[j];
            const int s2 = (s + 2 < FNSTEP) ? s + 2 : FNSTEP - 1;
#pragma unroll
            for (int c = 0; c < 4; ++c) xs[c] = *(const f4*)(xg + s2 * FSK + c * 4);
#pragma unroll
            for (int j = 0; j < 16; ++j) ws[j] = wg[(s2 * FSK + j) * E + lane];
        }
        const float* xnx = (s < FNSTEP - 1) ? xn : xc;
        const float* wnx = (s < FNSTEP - 1) ? wn : wc;
#pragma unroll
        for (int r = 0; r < FSK; ++r) {
            const int p = r & 1;
            fmablock(acc, xw[p], ww[p]);
            const float* xsrc = (r < FSK - 2) ? (xc + (r + 2) * 64)
                                              : (xnx + (r - (FSK - 2)) * 64);
            const float* wsrc = (r < FSK - 2) ? (wc + (r + 2) * 64)
                                              : (wnx + (r - (FSK - 2)) * 64);
            xw[p][0] = *(const f4*)(xsrc + tg * 8);
            xw[p][1] = *(const f4*)(xsrc + tg * 8 + 4);
            ww[p][0] = *(const f4*)(wsrc + eg * 8);
            ww[p][1] = *(const f4*)(wsrc + eg * 8 + 4);
        }
    }

    float* buf0 = smem;
    float* buf1 = smem + 4160;
    __syncthreads();
    if (w == 2) fb_tile_store(buf0, acc, tg, eg);
    if (w == 3) fb_tile_store(buf1, acc, tg, eg);
    __syncthreads();
    if (w == 0) fb_tile_addin(buf0, acc, tg, eg);
    if (w == 1) fb_tile_addin(buf1, acc, tg, eg);
    __syncthreads();
    if (w == 1) fb_tile_store(buf0, acc, tg, eg);
    __syncthreads();
    if (w == 0) {
        fb_tile_addin(buf0, acc, tg, eg);
        fb_tile_store(buf0, acc, tg, eg);
    }
    __syncthreads();

    float* logits = buf0;
    float* sw1 = smem + 8320; float* sw2 = smem + 8384;
    int*   si1 = (int*)(smem + 8448); int* si2 = (int*)(smem + 8512);

    if (w == 0) {
        float m1 = -3.4e38f, m2 = -3.4e38f;
        int i1 = 0, i2 = 0;
#pragma unroll
        for (int e = 0; e < E; ++e) {
            float v = logits[lane * 65 + e] + Bv[e];
            if (v > m1)      { m2 = m1; i2 = i1; m1 = v; i1 = e; }
            else if (v > m2) { m2 = v; i2 = e; }
        }
        float p = 1.0f / (1.0f + expf(m2 - m1));
        sw1[lane] = p; sw2[lane] = 1.0f - p;
        si1[lane] = i1; si2[lane] = i2;
    }
    __syncthreads();

    float4* o4 = (float4*)(out + (size_t)tok0 * E);
#pragma unroll
    for (int p5 = 0; p5 < 4; ++p5) {
        int idx = tid + p5 * 256;
        int tl  = idx >> 4;
        int e0  = (idx & 15) * 4;
        int a1 = si1[tl], a2 = si2[tl];
        float v1 = sw1[tl], v2 = sw2[tl];
        float4 v;
        v.x = (e0 + 0 == a1) ? v1 : (e0 + 0 == a2) ? v2 : 0.0f;
        v.y = (e0 + 1 == a1) ? v1 : (e0 + 1 == a2) ? v2 : 0.0f;
        v.z = (e0 + 2 == a1) ? v1 : (e0 + 2 == a2) ? v2 : 0.0f;
        v.w = (e0 + 3 == a1) ? v1 : (e0 + 3 == a2) ? v2 : 0.0f;
        o4[idx] = v;
    }
}

extern "C" void kernel_launch(void* const* d_in, const int* in_sizes, int n_in,
                              void* d_out, int out_size, void* d_ws, size_t ws_size,
                              hipStream_t stream) {
    const float* x = (const float*)d_in[0];
    const float* W = (const float*)d_in[1];
    const float* b = (const float*)d_in[2];
    float* out = (float*)d_out;

    const int tokens = in_sizes[0] / D;                          // 16384
    const size_t need = (size_t)NQ * tokens * E * sizeof(float); // 16 MB

    if (d_ws != nullptr && ws_size >= need && (tokens % TOK) == 0) {
        gating_mm<<<(tokens / TOK) * NQ, 256, 0, stream>>>(x, W, (float*)d_ws, tokens);
        gating_topk<<<tokens / TOK, 256, 0, stream>>>((const float*)d_ws, b, out, tokens);
    } else {
        gating_fb<<<tokens / TOK, 256, 0, stream>>>(x, W, b, out);
    }
}